// Round 27
// baseline (140.460 us; speedup 1.0000x reference)
//
#include <hip/hip_runtime.h>

#define DIM 768
#define HEADS 12
#define HDIM 64
#define B_ 8
#define N_ 1024
#define EPS 1e-5f
#define QPRE 0.18033688f   // 0.125 * log2(e): Q pre-scale -> softmax in log2 domain

typedef __bf16 bf16x8 __attribute__((ext_vector_type(8)));
typedef float  f32x4  __attribute__((ext_vector_type(4)));

using u16 = unsigned short;
using u32 = unsigned int;

static __device__ __forceinline__ u16 f2b_rne(float f){
    u32 u = __float_as_uint(f);
    u += 0x7fffu + ((u >> 16) & 1u);
    return (u16)(u >> 16);
}

// pack two f32 -> bf16x2 in one instr (T12 recipe; lo=src0, hi=src1)
static __device__ __forceinline__ u32 cvt_pk_bf16(float lo, float hi){
    u32 r;
    asm("v_cvt_pk_bf16_f32 %0, %1, %2" : "=v"(r) : "v"(lo), "v"(hi));
    return r;
}

// global -> LDS direct DMA, 16B per lane. LDS dest wave-uniform (HW adds lane*16).
static __device__ __forceinline__ void gl_lds16(const void* g, void* l){
    __builtin_amdgcn_global_load_lds(
        (const __attribute__((address_space(1))) unsigned int*)g,
        (__attribute__((address_space(3))) unsigned int*)l, 16, 0, 0);
}

// -------------------- fused cast fp32 -> bf16 (x, qkv_w, proj_w in one launch) --------------------
__global__ __launch_bounds__(256) void cast3_kernel(
    const float* __restrict__ s0, u16* __restrict__ d0, int n0,
    const float* __restrict__ s1, u16* __restrict__ d1, int n1,
    const float* __restrict__ s2, u16* __restrict__ d2, int n2)
{
    int i = blockIdx.x * 256 + threadIdx.x;
    const float* s; u16* d;
    if (i < n0)            { s = s0; d = d0; }
    else if (i < n0 + n1)  { s = s1; d = d1; i -= n0; }
    else if (i < n0+n1+n2) { s = s2; d = d2; i -= n0 + n1; }
    else return;
    const float4* p = (const float4*)s;
    float4 a = p[2*i], b = p[2*i+1];
    uint4 r;
    r.x = (u32)f2b_rne(a.x) | ((u32)f2b_rne(a.y) << 16);
    r.y = (u32)f2b_rne(a.z) | ((u32)f2b_rne(a.w) << 16);
    r.z = (u32)f2b_rne(b.x) | ((u32)f2b_rne(b.y) << 16);
    r.w = (u32)f2b_rne(b.z) | ((u32)f2b_rne(b.w) << 16);
    ((uint4*)d)[i] = r;
}

// -------------------- Kernel 1: QKV GEMM (dbuf + counted vmcnt) + bias + LN --------------------
__global__ __launch_bounds__(256) void qkv_gemm_ln(
    const u16* __restrict__ xb, const u16* __restrict__ wb,
    const float* __restrict__ bias,
    const float* __restrict__ qn_w, const float* __restrict__ qn_b,
    const float* __restrict__ kn_w, const float* __restrict__ kn_b,
    u16* __restrict__ Q, u16* __restrict__ K, u16* __restrict__ VT)
{
    __shared__ __align__(16) unsigned char Asl[2][128*128];   // dbuf [128 rows][64 bf16]
    __shared__ __align__(16) unsigned char Bsl[2][128*128];
    const int t = threadIdx.x;
    const int lane = t & 63, wid = t >> 6;
    const int wr = wid >> 1, wc = wid & 1;
    const int l15 = lane & 15, l4 = lane >> 4;
    const int lr  = lane >> 3;
    const int lcs = ((lane & 7) ^ lr & 7) * 16;            // pre-swizzled src chunk
    const int rsw = (l15 & 7) << 4;                        // read-side XOR

    const int b0 = blockIdx.x;
    const int lg = (b0 & 7) * 144 + (b0 >> 3);
    const int col0 = (lg % 18) * 128, row0 = (lg / 18) * 128;

    f32x4 acc[4][4];
    #pragma unroll
    for (int m = 0; m < 4; ++m)
        #pragma unroll
        for (int n = 0; n < 4; ++n) acc[m][n] = f32x4{0.f,0.f,0.f,0.f};

    // hoisted per-lane staging bases
    const unsigned char* aSrc = (const unsigned char*)xb + (size_t)(row0 + lr)*1536 + lcs;
    const unsigned char* bSrc = (const unsigned char*)wb + (size_t)(col0 + lr)*1536 + lcs;

    auto stage = [&](int buf, int k0s){
        #pragma unroll
        for (int c = 0; c < 4; ++c) {
            int rg = wid*32 + c*8;      // 8 rows x 128B = 1KB per call
            gl_lds16(aSrc + (size_t)rg*1536 + k0s*2, Asl[buf] + rg*128);
            gl_lds16(bSrc + (size_t)rg*1536 + k0s*2, Bsl[buf] + rg*128);
        }
    };

    stage(0, 0);   // 8 vmem ops in flight

    for (int step = 0; step < 12; ++step) {
        const int cur = step & 1;
        if (step < 11) {
            stage(cur ^ 1, (step + 1) * 64);                       // +8 newer ops
            asm volatile("s_waitcnt vmcnt(8)" ::: "memory");       // tile-cur (oldest 8) done
        } else {
            asm volatile("s_waitcnt vmcnt(0)" ::: "memory");
        }
        __builtin_amdgcn_s_barrier();   // all waves: tile cur fully staged

        #pragma unroll
        for (int s = 0; s < 2; ++s) {
            bf16x8 af[4], bfr[4];
            #pragma unroll
            for (int m = 0; m < 4; ++m)
                af[m] = *(const bf16x8*)(Asl[cur] + (wr*64 + m*16 + l15)*128 + ((l4*16 + s*64) ^ rsw));
            #pragma unroll
            for (int n = 0; n < 4; ++n)
                bfr[n] = *(const bf16x8*)(Bsl[cur] + (wc*64 + n*16 + l15)*128 + ((l4*16 + s*64) ^ rsw));
            #pragma unroll
            for (int m = 0; m < 4; ++m)
                #pragma unroll
                for (int n = 0; n < 4; ++n)
                    acc[m][n] = __builtin_amdgcn_mfma_f32_16x16x32_bf16(af[m], bfr[n], acc[m][n], 0, 0, 0);
        }
        __builtin_amdgcn_s_barrier();   // all reads of buf[cur] consumed -> overwrite safe
    }

    const int cg0 = col0 + wc*64;
    const int which = cg0 / DIM;           // 0=q 1=k 2=v
    const int h = (cg0 % DIM) / HDIM;

    float bias_v[4];
    #pragma unroll
    for (int n = 0; n < 4; ++n) bias_v[n] = bias[cg0 + n*16 + l15];
    #pragma unroll
    for (int m = 0; m < 4; ++m)
        #pragma unroll
        for (int n = 0; n < 4; ++n)
            #pragma unroll
            for (int r = 0; r < 4; ++r) acc[m][n][r] += bias_v[n];

    // A/B LDS dead after loop-final barrier; per-wave 8KB transpose tile in Asl
    unsigned char* Tw = &Asl[0][0] + wid * 8192;

    if (which < 2) {
        const float* lwp = (which == 0) ? qn_w : kn_w;
        const float* lbp = (which == 0) ? qn_b : kn_b;
        const float qsc = (which == 0) ? QPRE : 1.0f;      // fold softmax scale+log2e into Q
        float lw_v[4], lb_v[4];
        #pragma unroll
        for (int n = 0; n < 4; ++n) { lw_v[n] = lwp[n*16 + l15] * qsc; lb_v[n] = lbp[n*16 + l15] * qsc; }

        #pragma unroll
        for (int m = 0; m < 4; ++m)
            #pragma unroll
            for (int r = 0; r < 4; ++r) {
                float s = 0.f, s2 = 0.f;
                #pragma unroll
                for (int n = 0; n < 4; ++n) { float v = acc[m][n][r]; s += v; s2 += v*v; }
                #pragma unroll
                for (int off = 1; off < 16; off <<= 1) {
                    s  += __shfl_xor(s,  off, 64);
                    s2 += __shfl_xor(s2, off, 64);
                }
                float mu  = s * (1.f/64.f);
                float var = s2 * (1.f/64.f) - mu*mu;
                float rs  = rsqrtf(var + EPS);
                #pragma unroll
                for (int n = 0; n < 4; ++n)
                    acc[m][n][r] = (acc[m][n][r] - mu) * rs * lw_v[n] + lb_v[n];
            }

        #pragma unroll
        for (int m = 0; m < 4; ++m)
            #pragma unroll
            for (int n = 0; n < 4; ++n)
                #pragma unroll
                for (int r = 0; r < 4; ++r)
                    *(u16*)(Tw + (m*16 + l4*4 + r)*128 + (n*16 + l15)*2) = f2b_rne(acc[m][n][r]);

        u16* dst = (which == 0) ? Q : K;
        const int tok0 = row0 + wr*64;
        const int b = tok0 >> 10, n0 = tok0 & 1023;
        const size_t bh = (size_t)(b * HEADS + h);
        #pragma unroll
        for (int i = 0; i < 8; ++i) {
            int row = i*8 + (lane >> 3);
            int d0  = (lane & 7) * 8;
            uint4 val = *(const uint4*)(Tw + row*128 + d0*2);
            *(uint4*)(dst + (bh * N_ + n0 + row) * HDIM + d0) = val;
        }
    } else {
        #pragma unroll
        for (int n = 0; n < 4; ++n)
            #pragma unroll
            for (int m = 0; m < 4; ++m)
                #pragma unroll
                for (int r = 0; r < 4; ++r)
                    *(u16*)(Tw + (n*16 + l15)*128 + (m*16 + l4*4 + r)*2) = f2b_rne(acc[m][n][r]);

        const int tok0 = row0 + wr*64;
        const int b = tok0 >> 10, n0v = tok0 & 1023;
        const size_t bh = (size_t)(b * HEADS + h);
        #pragma unroll
        for (int i = 0; i < 8; ++i) {
            int d  = i*8 + (lane >> 3);
            int tk = (lane & 7) * 8;
            uint4 val = *(const uint4*)(Tw + d*128 + tk*2);
            *(uint4*)(VT + (bh * HDIM + d) * N_ + n0v + tk) = val;
        }
    }
}

// -------------------- Kernel 2: flash attention (QBLK=128, l-via-MFMA) --------------------
// Proven skeleton; softmax row-sum moved off the VALU: lsum = mfma(ones, P^T)
// accumulates l[q] in the matrix pipe (also removes the final shfl reduce).
__global__ __launch_bounds__(256) void attn_mfma(
    const u16* __restrict__ Q, const u16* __restrict__ K,
    const u16* __restrict__ VT, u16* __restrict__ A)
{
    __shared__ __align__(16) unsigned char Ks[2][64*128];
    __shared__ __align__(16) unsigned char Vs[2][64*128];
    __shared__ __align__(16) unsigned char Ps[4*4352];     // per-wave P [32 q][128B swz] / epilogue [32 q][132B]
    const int t = threadIdx.x, lane = t & 63, w = t >> 6;
    const int l15 = lane & 15, l4 = lane >> 4;
    const int lr  = lane >> 3;
    const int lcs = ((lane & 7) ^ lr & 7) * 16;
    const int rsw = (l15 & 7) << 4;                        // K/V tile read swizzle (row-keyed)
    const int psw = (l15 & 7) << 4;                        // P row swizzle (row&7 = l15&7)

    // grid 768 = 8 * 96; qt fastest within XCD chunk -> KV L2 reuse
    const int b0 = blockIdx.x;
    const int lg = (b0 & 7) * 96 + (b0 >> 3);
    const int qt = lg & 7, bh = lg >> 3;
    const size_t base = (size_t)bh * (N_ * HDIM);

    bf16x8 qa[2][2];   // [q-group][k-slice]
    #pragma unroll
    for (int qg = 0; qg < 2; ++qg) {
        const unsigned char* qb = (const unsigned char*)(Q + base + (size_t)(qt*128 + w*32 + qg*16 + l15) * HDIM);
        qa[qg][0] = *(const bf16x8*)(qb + l4*16);
        qa[qg][1] = *(const bf16x8*)(qb + l4*16 + 64);
    }

    bf16x8 ones;
    #pragma unroll
    for (int i = 0; i < 8; ++i) ones[i] = (__bf16)1.0f;

    f32x4 lsum[2];                         // l[q] accumulated via MFMA (all rows equal)
    f32x4 o[2][4];                         // O^T[d = m*16+l4*4+r][q]
    #pragma unroll
    for (int qg = 0; qg < 2; ++qg) {
        lsum[qg] = f32x4{0.f,0.f,0.f,0.f};
        #pragma unroll
        for (int m = 0; m < 4; ++m) o[qg][m] = f32x4{0.f,0.f,0.f,0.f};
    }

    unsigned char* Pw = Ps + w*4352;

    const unsigned char* kSrc = (const unsigned char*)K  + base*2 + (size_t)(w*16 + lr)*128  + lcs;
    const unsigned char* vSrc = (const unsigned char*)VT + base*2 + (size_t)(w*16 + lr)*2048 + lcs;
    unsigned char* kDst0 = Ks[0] + w*16*128;
    unsigned char* vDst0 = Vs[0] + w*16*128;

    auto stage = [&](int buf, int kt2){
        #pragma unroll
        for (int c = 0; c < 2; ++c) {
            gl_lds16(kSrc + (size_t)kt2*8192 + c*1024,  kDst0 + buf*8192 + c*1024);
            gl_lds16(vSrc + kt2*128 + c*16384,          vDst0 + buf*8192 + c*1024);
        }
    };

    stage(0, 0);   // 4 vmem ops in flight

    for (int kt = 0; kt < 16; ++kt) {
        const int cur = kt & 1;
        if (kt < 15) {
            stage(cur ^ 1, kt + 1);                                // +4 newer ops
            asm volatile("s_waitcnt vmcnt(4)" ::: "memory");       // tile-cur (oldest 4) done
        } else {
            asm volatile("s_waitcnt vmcnt(0)" ::: "memory");
        }
        __builtin_amdgcn_s_barrier();

        // S^T = K Q^T (log2 domain); kb reused across both q-groups
        f32x4 sv[2][4];
        __builtin_amdgcn_s_setprio(1);
        #pragma unroll
        for (int n = 0; n < 4; ++n) {
            sv[0][n] = f32x4{0.f,0.f,0.f,0.f};
            sv[1][n] = f32x4{0.f,0.f,0.f,0.f};
            #pragma unroll
            for (int s = 0; s < 2; ++s) {
                bf16x8 kb = *(const bf16x8*)(Ks[cur] + (n*16 + l15)*128 + ((l4*16 + s*64) ^ rsw));
                sv[0][n] = __builtin_amdgcn_mfma_f32_16x16x32_bf16(kb, qa[0][s], sv[0][n], 0, 0, 0);
                sv[1][n] = __builtin_amdgcn_mfma_f32_16x16x32_bf16(kb, qa[1][s], sv[1][n], 0, 0, 0);
            }
        }
        __builtin_amdgcn_s_setprio(0);

        // P = exp2(S'); pack pairs -> P[q][kv] (b64 writes); row-sum deferred to MFMA
        #pragma unroll
        for (int qg = 0; qg < 2; ++qg)
            #pragma unroll
            for (int n = 0; n < 4; ++n) {
                float p0 = exp2f(sv[qg][n][0]), p1 = exp2f(sv[qg][n][1]);
                float p2 = exp2f(sv[qg][n][2]), p3 = exp2f(sv[qg][n][3]);
                uint2 pw;
                pw.x = cvt_pk_bf16(p0, p1);
                pw.y = cvt_pk_bf16(p2, p3);
                *(uint2*)(Pw + (qg*16 + l15)*128 + ((n*32 + l4*8) ^ psw)) = pw;
            }

        // O^T += VT * P^T ; vb reused across both q-groups; l via ones-MFMA
        __builtin_amdgcn_s_setprio(1);
        #pragma unroll
        for (int s = 0; s < 2; ++s) {
            bf16x8 pb0 = *(const bf16x8*)(Pw + (l15)*128      + ((s*64 + l4*16) ^ psw));
            bf16x8 pb1 = *(const bf16x8*)(Pw + (16 + l15)*128 + ((s*64 + l4*16) ^ psw));
            lsum[0] = __builtin_amdgcn_mfma_f32_16x16x32_bf16(ones, pb0, lsum[0], 0, 0, 0);
            lsum[1] = __builtin_amdgcn_mfma_f32_16x16x32_bf16(ones, pb1, lsum[1], 0, 0, 0);
            #pragma unroll
            for (int m = 0; m < 4; ++m) {
                bf16x8 vb = *(const bf16x8*)(Vs[cur] + (m*16 + l15)*128 + ((l4*16 + s*64) ^ rsw));
                o[0][m] = __builtin_amdgcn_mfma_f32_16x16x32_bf16(vb, pb0, o[0][m], 0, 0, 0);
                o[1][m] = __builtin_amdgcn_mfma_f32_16x16x32_bf16(vb, pb1, o[1][m], 0, 0, 0);
            }
        }
        __builtin_amdgcn_s_setprio(0);

        __builtin_amdgcn_s_barrier();   // reads of buf[cur] consumed -> overwrite safe
    }

    // l[q] complete in lsum (every row identical; MFMA summed the kv axis)
    const float inv0 = 1.f / lsum[0][0], inv1 = 1.f / lsum[1][0];

    // epilogue: stage O rows [32 q][132B], then 128B-contiguous stores
    const int b = bh / HEADS, h = bh % HEADS;
    #pragma unroll
    for (int m = 0; m < 4; ++m)
        #pragma unroll
        for (int r = 0; r < 4; ++r) {
            *(u16*)(Pw + l15*132        + (m*16 + l4*4 + r)*2) = f2b_rne(o[0][m][r] * inv0);
            *(u16*)(Pw + (16 + l15)*132 + (m*16 + l4*4 + r)*2) = f2b_rne(o[1][m][r] * inv1);
        }
    #pragma unroll
    for (int i = 0; i < 4; ++i) {
        int row = i*8 + (lane >> 3);              // q-row within wave's 32
        int d0  = (lane & 7) * 8;
        uint4 val = *(const uint4*)(Pw + row*132 + d0*2);
        int tok = qt*128 + w*32 + row;
        *(uint4*)(A + (((size_t)b * N_ + tok) * HEADS + h) * HDIM + d0) = val;
    }
}

// -------------------- Kernel 3: output projection (dbuf + counted vmcnt, fp32 out) --------------------
__global__ __launch_bounds__(256) void proj_gemm(
    const u16* __restrict__ Ab, const u16* __restrict__ wb,
    const float* __restrict__ bias, float* __restrict__ out)
{
    __shared__ __align__(16) unsigned char Asl[2][128*128];
    __shared__ __align__(16) unsigned char Bsl[2][128*128];
    const int t = threadIdx.x;
    const int lane = t & 63, wid = t >> 6;
    const int wr = wid >> 1, wc = wid & 1;
    const int l15 = lane & 15, l4 = lane >> 4;
    const int lr  = lane >> 3;
    const int lcs = ((lane & 7) ^ lr & 7) * 16;
    const int rsw = (l15 & 7) << 4;

    const int b0 = blockIdx.x;
    const int lg = (b0 & 7) * 48 + (b0 >> 3);
    const int col0 = (lg % 6) * 128, row0 = (lg / 6) * 128;

    f32x4 acc[4][4];
    #pragma unroll
    for (int m = 0; m < 4; ++m)
        #pragma unroll
        for (int n = 0; n < 4; ++n) acc[m][n] = f32x4{0.f,0.f,0.f,0.f};

    const unsigned char* aSrc = (const unsigned char*)Ab + (size_t)(row0 + lr)*1536 + lcs;
    const unsigned char* bSrc = (const unsigned char*)wb + (size_t)(col0 + lr)*1536 + lcs;

    auto stage = [&](int buf, int k0s){
        #pragma unroll
        for (int c = 0; c < 4; ++c) {
            int rg = wid*32 + c*8;
            gl_lds16(aSrc + (size_t)rg*1536 + k0s*2, Asl[buf] + rg*128);
            gl_lds16(bSrc + (size_t)rg*1536 + k0s*2, Bsl[buf] + rg*128);
        }
    };

    stage(0, 0);

    for (int step = 0; step < 12; ++step) {
        const int cur = step & 1;
        if (step < 11) {
            stage(cur ^ 1, (step + 1) * 64);
            asm volatile("s_waitcnt vmcnt(8)" ::: "memory");
        } else {
            asm volatile("s_waitcnt vmcnt(0)" ::: "memory");
        }
        __builtin_amdgcn_s_barrier();

        #pragma unroll
        for (int s = 0; s < 2; ++s) {
            bf16x8 af[4], bfr[4];
            #pragma unroll
            for (int m = 0; m < 4; ++m)
                af[m] = *(const bf16x8*)(Asl[cur] + (wr*64 + m*16 + l15)*128 + ((l4*16 + s*64) ^ rsw));
            #pragma unroll
            for (int n = 0; n < 4; ++n)
                bfr[n] = *(const bf16x8*)(Bsl[cur] + (wc*64 + n*16 + l15)*128 + ((l4*16 + s*64) ^ rsw));
            #pragma unroll
            for (int m = 0; m < 4; ++m)
                #pragma unroll
                for (int n = 0; n < 4; ++n)
                    acc[m][n] = __builtin_amdgcn_mfma_f32_16x16x32_bf16(af[m], bfr[n], acc[m][n], 0, 0, 0);
        }
        __builtin_amdgcn_s_barrier();
    }

    float bias_v[4];
    #pragma unroll
    for (int n = 0; n < 4; ++n) bias_v[n] = bias[col0 + wc*64 + n*16 + l15];
    #pragma unroll
    for (int m = 0; m < 4; ++m)
        #pragma unroll
        for (int r = 0; r < 4; ++r) {
            int rg = row0 + wr*64 + m*16 + l4*4 + r;
            #pragma unroll
            for (int n = 0; n < 4; ++n)
                out[(size_t)rg * DIM + col0 + wc*64 + n*16 + l15] = acc[m][n][r] + bias_v[n];
        }
}

extern "C" void kernel_launch(void* const* d_in, const int* in_sizes, int n_in,
                              void* d_out, int out_size, void* d_ws, size_t ws_size,
                              hipStream_t stream)
{
    const float* x      = (const float*)d_in[0];
    const float* qkv_w  = (const float*)d_in[1];
    const float* qkv_b  = (const float*)d_in[2];
    const float* qn_w   = (const float*)d_in[3];
    const float* qn_b   = (const float*)d_in[4];
    const float* kn_w   = (const float*)d_in[5];
    const float* kn_b   = (const float*)d_in[6];
    const float* proj_w = (const float*)d_in[7];
    const float* proj_b = (const float*)d_in[8];
    float* out = (float*)d_out;

    const size_t XE  = (size_t)B_ * N_ * DIM;   // 6291456
    const size_t QWE = (size_t)3 * DIM * DIM;   // 1769472
    const size_t PWE = (size_t)DIM * DIM;       // 589824

    u16* xb  = (u16*)d_ws;
    u16* qwb = xb  + XE;
    u16* pwb = qwb + QWE;
    u16* Qb  = pwb + PWE;
    u16* Kb  = Qb  + XE;
    u16* VTb = Kb  + XE;
    u16* Ab  = VTb + XE;    // total 67.6 MB

    const int n0 = (int)(XE/8), n1 = (int)(QWE/8), n2 = (int)(PWE/8);
    cast3_kernel<<<(n0 + n1 + n2 + 255)/256, 256, 0, stream>>>(x, xb, n0, qkv_w, qwb, n1, proj_w, pwb, n2);

    qkv_gemm_ln<<<dim3(1152), 256, 0, stream>>>(xb, qwb, qkv_b, qn_w, qn_b,
                                                kn_w, kn_b, Qb, Kb, VTb);
    attn_mfma<<<dim3(768), 256, 0, stream>>>(Qb, Kb, VTb, Ab);
    proj_gemm<<<dim3(384), 256, 0, stream>>>(Ab, pwb, proj_b, out);
}

// Round 28
// 131.714 us; speedup vs baseline: 1.0664x; 1.0664x over previous
//
#include <hip/hip_runtime.h>

#define DIM 768
#define HEADS 12
#define HDIM 64
#define B_ 8
#define N_ 1024
#define EPS 1e-5f
#define QPRE 0.18033688f   // 0.125 * log2(e): Q pre-scale -> softmax in log2 domain

typedef __bf16 bf16x8 __attribute__((ext_vector_type(8)));
typedef float  f32x4  __attribute__((ext_vector_type(4)));

using u16 = unsigned short;
using u32 = unsigned int;

static __device__ __forceinline__ u16 f2b_rne(float f){
    u32 u = __float_as_uint(f);
    u += 0x7fffu + ((u >> 16) & 1u);
    return (u16)(u >> 16);
}

// pack two f32 -> bf16x2 in one instr (T12 recipe; lo=src0, hi=src1)
static __device__ __forceinline__ u32 cvt_pk_bf16(float lo, float hi){
    u32 r;
    asm("v_cvt_pk_bf16_f32 %0, %1, %2" : "=v"(r) : "v"(lo), "v"(hi));
    return r;
}

// global -> LDS direct DMA, 16B per lane. LDS dest wave-uniform (HW adds lane*16).
static __device__ __forceinline__ void gl_lds16(const void* g, void* l){
    __builtin_amdgcn_global_load_lds(
        (const __attribute__((address_space(1))) unsigned int*)g,
        (__attribute__((address_space(3))) unsigned int*)l, 16, 0, 0);
}

// -------------------- fused cast fp32 -> bf16 (x, qkv_w, proj_w in one launch) --------------------
__global__ __launch_bounds__(256) void cast3_kernel(
    const float* __restrict__ s0, u16* __restrict__ d0, int n0,
    const float* __restrict__ s1, u16* __restrict__ d1, int n1,
    const float* __restrict__ s2, u16* __restrict__ d2, int n2)
{
    int i = blockIdx.x * 256 + threadIdx.x;
    const float* s; u16* d;
    if (i < n0)            { s = s0; d = d0; }
    else if (i < n0 + n1)  { s = s1; d = d1; i -= n0; }
    else if (i < n0+n1+n2) { s = s2; d = d2; i -= n0 + n1; }
    else return;
    const float4* p = (const float4*)s;
    float4 a = p[2*i], b = p[2*i+1];
    uint4 r;
    r.x = (u32)f2b_rne(a.x) | ((u32)f2b_rne(a.y) << 16);
    r.y = (u32)f2b_rne(a.z) | ((u32)f2b_rne(a.w) << 16);
    r.z = (u32)f2b_rne(b.x) | ((u32)f2b_rne(b.y) << 16);
    r.w = (u32)f2b_rne(b.z) | ((u32)f2b_rne(b.w) << 16);
    ((uint4*)d)[i] = r;
}

// -------------------- Kernel 1: QKV GEMM (dbuf + counted vmcnt) + bias + LN --------------------
__global__ __launch_bounds__(256) void qkv_gemm_ln(
    const u16* __restrict__ xb, const u16* __restrict__ wb,
    const float* __restrict__ bias,
    const float* __restrict__ qn_w, const float* __restrict__ qn_b,
    const float* __restrict__ kn_w, const float* __restrict__ kn_b,
    u16* __restrict__ Q, u16* __restrict__ K, u16* __restrict__ VT)
{
    __shared__ __align__(16) unsigned char Asl[2][128*128];   // dbuf [128 rows][64 bf16]
    __shared__ __align__(16) unsigned char Bsl[2][128*128];
    const int t = threadIdx.x;
    const int lane = t & 63, wid = t >> 6;
    const int wr = wid >> 1, wc = wid & 1;
    const int l15 = lane & 15, l4 = lane >> 4;
    const int lr  = lane >> 3;
    const int lcs = ((lane & 7) ^ lr & 7) * 16;            // pre-swizzled src chunk
    const int rsw = (l15 & 7) << 4;                        // read-side XOR

    const int b0 = blockIdx.x;
    const int lg = (b0 & 7) * 144 + (b0 >> 3);
    const int col0 = (lg % 18) * 128, row0 = (lg / 18) * 128;

    f32x4 acc[4][4];
    #pragma unroll
    for (int m = 0; m < 4; ++m)
        #pragma unroll
        for (int n = 0; n < 4; ++n) acc[m][n] = f32x4{0.f,0.f,0.f,0.f};

    // hoisted per-lane staging bases
    const unsigned char* aSrc = (const unsigned char*)xb + (size_t)(row0 + lr)*1536 + lcs;
    const unsigned char* bSrc = (const unsigned char*)wb + (size_t)(col0 + lr)*1536 + lcs;

    auto stage = [&](int buf, int k0s){
        #pragma unroll
        for (int c = 0; c < 4; ++c) {
            int rg = wid*32 + c*8;      // 8 rows x 128B = 1KB per call
            gl_lds16(aSrc + (size_t)rg*1536 + k0s*2, Asl[buf] + rg*128);
            gl_lds16(bSrc + (size_t)rg*1536 + k0s*2, Bsl[buf] + rg*128);
        }
    };

    stage(0, 0);   // 8 vmem ops in flight

    for (int step = 0; step < 12; ++step) {
        const int cur = step & 1;
        if (step < 11) {
            stage(cur ^ 1, (step + 1) * 64);                       // +8 newer ops
            asm volatile("s_waitcnt vmcnt(8)" ::: "memory");       // tile-cur (oldest 8) done
        } else {
            asm volatile("s_waitcnt vmcnt(0)" ::: "memory");
        }
        __builtin_amdgcn_s_barrier();   // all waves: tile cur fully staged

        #pragma unroll
        for (int s = 0; s < 2; ++s) {
            bf16x8 af[4], bfr[4];
            #pragma unroll
            for (int m = 0; m < 4; ++m)
                af[m] = *(const bf16x8*)(Asl[cur] + (wr*64 + m*16 + l15)*128 + ((l4*16 + s*64) ^ rsw));
            #pragma unroll
            for (int n = 0; n < 4; ++n)
                bfr[n] = *(const bf16x8*)(Bsl[cur] + (wc*64 + n*16 + l15)*128 + ((l4*16 + s*64) ^ rsw));
            #pragma unroll
            for (int m = 0; m < 4; ++m)
                #pragma unroll
                for (int n = 0; n < 4; ++n)
                    acc[m][n] = __builtin_amdgcn_mfma_f32_16x16x32_bf16(af[m], bfr[n], acc[m][n], 0, 0, 0);
        }
        __builtin_amdgcn_s_barrier();   // all reads of buf[cur] consumed -> overwrite safe
    }

    const int cg0 = col0 + wc*64;
    const int which = cg0 / DIM;           // 0=q 1=k 2=v
    const int h = (cg0 % DIM) / HDIM;

    float bias_v[4];
    #pragma unroll
    for (int n = 0; n < 4; ++n) bias_v[n] = bias[cg0 + n*16 + l15];
    #pragma unroll
    for (int m = 0; m < 4; ++m)
        #pragma unroll
        for (int n = 0; n < 4; ++n)
            #pragma unroll
            for (int r = 0; r < 4; ++r) acc[m][n][r] += bias_v[n];

    // A/B LDS dead after loop-final barrier; per-wave 8KB transpose tile in Asl
    unsigned char* Tw = &Asl[0][0] + wid * 8192;

    if (which < 2) {
        const float* lwp = (which == 0) ? qn_w : kn_w;
        const float* lbp = (which == 0) ? qn_b : kn_b;
        const float qsc = (which == 0) ? QPRE : 1.0f;      // fold softmax scale+log2e into Q
        float lw_v[4], lb_v[4];
        #pragma unroll
        for (int n = 0; n < 4; ++n) { lw_v[n] = lwp[n*16 + l15] * qsc; lb_v[n] = lbp[n*16 + l15] * qsc; }

        #pragma unroll
        for (int m = 0; m < 4; ++m)
            #pragma unroll
            for (int r = 0; r < 4; ++r) {
                float s = 0.f, s2 = 0.f;
                #pragma unroll
                for (int n = 0; n < 4; ++n) { float v = acc[m][n][r]; s += v; s2 += v*v; }
                #pragma unroll
                for (int off = 1; off < 16; off <<= 1) {
                    s  += __shfl_xor(s,  off, 64);
                    s2 += __shfl_xor(s2, off, 64);
                }
                float mu  = s * (1.f/64.f);
                float var = s2 * (1.f/64.f) - mu*mu;
                float rs  = rsqrtf(var + EPS);
                #pragma unroll
                for (int n = 0; n < 4; ++n)
                    acc[m][n][r] = (acc[m][n][r] - mu) * rs * lw_v[n] + lb_v[n];
            }

        #pragma unroll
        for (int m = 0; m < 4; ++m)
            #pragma unroll
            for (int n = 0; n < 4; ++n)
                #pragma unroll
                for (int r = 0; r < 4; ++r)
                    *(u16*)(Tw + (m*16 + l4*4 + r)*128 + (n*16 + l15)*2) = f2b_rne(acc[m][n][r]);

        u16* dst = (which == 0) ? Q : K;
        const int tok0 = row0 + wr*64;
        const int b = tok0 >> 10, n0 = tok0 & 1023;
        const size_t bh = (size_t)(b * HEADS + h);
        #pragma unroll
        for (int i = 0; i < 8; ++i) {
            int row = i*8 + (lane >> 3);
            int d0  = (lane & 7) * 8;
            uint4 val = *(const uint4*)(Tw + row*128 + d0*2);
            *(uint4*)(dst + (bh * N_ + n0 + row) * HDIM + d0) = val;
        }
    } else {
        #pragma unroll
        for (int n = 0; n < 4; ++n)
            #pragma unroll
            for (int m = 0; m < 4; ++m)
                #pragma unroll
                for (int r = 0; r < 4; ++r)
                    *(u16*)(Tw + (n*16 + l15)*128 + (m*16 + l4*4 + r)*2) = f2b_rne(acc[m][n][r]);

        const int tok0 = row0 + wr*64;
        const int b = tok0 >> 10, n0v = tok0 & 1023;
        const size_t bh = (size_t)(b * HEADS + h);
        #pragma unroll
        for (int i = 0; i < 8; ++i) {
            int d  = i*8 + (lane >> 3);
            int tk = (lane & 7) * 8;
            uint4 val = *(const uint4*)(Tw + d*128 + tk*2);
            *(uint4*)(VT + (bh * HDIM + d) * N_ + n0v + tk) = val;
        }
    }
}

// -------------------- Kernel 2: flash attention (QBLK=128, staged, counted vmcnt, setprio) ----
// Each block serves 128 q rows (2 q-groups of 16 per wave) -> staging/barrier
// costs amortized 2x, kb/vb fragments reused across both q-groups.
__global__ __launch_bounds__(256) void attn_mfma(
    const u16* __restrict__ Q, const u16* __restrict__ K,
    const u16* __restrict__ VT, u16* __restrict__ A)
{
    __shared__ __align__(16) unsigned char Ks[2][64*128];
    __shared__ __align__(16) unsigned char Vs[2][64*128];
    __shared__ __align__(16) unsigned char Ps[4*4352];     // per-wave P [32 q][128B swz] / epilogue [32 q][132B]
    const int t = threadIdx.x, lane = t & 63, w = t >> 6;
    const int l15 = lane & 15, l4 = lane >> 4;
    const int lr  = lane >> 3;
    const int lcs = ((lane & 7) ^ lr & 7) * 16;
    const int rsw = (l15 & 7) << 4;                        // K/V tile read swizzle (row-keyed)
    const int psw = (l15 & 7) << 4;                        // P row swizzle (row&7 = l15&7)

    // grid 768 = 8 * 96; qt fastest within XCD chunk -> KV L2 reuse
    const int b0 = blockIdx.x;
    const int lg = (b0 & 7) * 96 + (b0 >> 3);
    const int qt = lg & 7, bh = lg >> 3;
    const size_t base = (size_t)bh * (N_ * HDIM);

    bf16x8 qa[2][2];   // [q-group][k-slice]
    #pragma unroll
    for (int qg = 0; qg < 2; ++qg) {
        const unsigned char* qb = (const unsigned char*)(Q + base + (size_t)(qt*128 + w*32 + qg*16 + l15) * HDIM);
        qa[qg][0] = *(const bf16x8*)(qb + l4*16);
        qa[qg][1] = *(const bf16x8*)(qb + l4*16 + 64);
    }

    float l_run[2] = {0.f, 0.f};           // scalar per q-group (lane owns q = qg*16+l15)
    f32x4 o[2][4];                         // O^T[d = m*16+l4*4+r][q]
    #pragma unroll
    for (int qg = 0; qg < 2; ++qg)
        #pragma unroll
        for (int m = 0; m < 4; ++m) o[qg][m] = f32x4{0.f,0.f,0.f,0.f};

    unsigned char* Pw = Ps + w*4352;

    const unsigned char* kSrc = (const unsigned char*)K  + base*2 + (size_t)(w*16 + lr)*128  + lcs;
    const unsigned char* vSrc = (const unsigned char*)VT + base*2 + (size_t)(w*16 + lr)*2048 + lcs;
    unsigned char* kDst0 = Ks[0] + w*16*128;
    unsigned char* vDst0 = Vs[0] + w*16*128;

    auto stage = [&](int buf, int kt2){
        #pragma unroll
        for (int c = 0; c < 2; ++c) {
            gl_lds16(kSrc + (size_t)kt2*8192 + c*1024,  kDst0 + buf*8192 + c*1024);
            gl_lds16(vSrc + kt2*128 + c*16384,          vDst0 + buf*8192 + c*1024);
        }
    };

    stage(0, 0);   // 4 vmem ops in flight

    for (int kt = 0; kt < 16; ++kt) {
        const int cur = kt & 1;
        if (kt < 15) {
            stage(cur ^ 1, kt + 1);                                // +4 newer ops
            asm volatile("s_waitcnt vmcnt(4)" ::: "memory");       // tile-cur (oldest 4) done
        } else {
            asm volatile("s_waitcnt vmcnt(0)" ::: "memory");
        }
        __builtin_amdgcn_s_barrier();

        // S^T = K Q^T (log2 domain); kb reused across both q-groups
        f32x4 sv[2][4];
        __builtin_amdgcn_s_setprio(1);
        #pragma unroll
        for (int n = 0; n < 4; ++n) {
            sv[0][n] = f32x4{0.f,0.f,0.f,0.f};
            sv[1][n] = f32x4{0.f,0.f,0.f,0.f};
            #pragma unroll
            for (int s = 0; s < 2; ++s) {
                bf16x8 kb = *(const bf16x8*)(Ks[cur] + (n*16 + l15)*128 + ((l4*16 + s*64) ^ rsw));
                sv[0][n] = __builtin_amdgcn_mfma_f32_16x16x32_bf16(kb, qa[0][s], sv[0][n], 0, 0, 0);
                sv[1][n] = __builtin_amdgcn_mfma_f32_16x16x32_bf16(kb, qa[1][s], sv[1][n], 0, 0, 0);
            }
        }
        __builtin_amdgcn_s_setprio(0);

        // P = exp2(S'), lane-local row sums; pack pairs -> P[q][kv] (b64 writes)
        #pragma unroll
        for (int qg = 0; qg < 2; ++qg)
            #pragma unroll
            for (int n = 0; n < 4; ++n) {
                float p0 = exp2f(sv[qg][n][0]), p1 = exp2f(sv[qg][n][1]);
                float p2 = exp2f(sv[qg][n][2]), p3 = exp2f(sv[qg][n][3]);
                l_run[qg] += (p0 + p1) + (p2 + p3);
                uint2 pw;
                pw.x = cvt_pk_bf16(p0, p1);
                pw.y = cvt_pk_bf16(p2, p3);
                *(uint2*)(Pw + (qg*16 + l15)*128 + ((n*32 + l4*8) ^ psw)) = pw;
            }

        // O^T += VT * P^T ; vb reused across both q-groups
        __builtin_amdgcn_s_setprio(1);
        #pragma unroll
        for (int s = 0; s < 2; ++s) {
            bf16x8 pb0 = *(const bf16x8*)(Pw + (l15)*128      + ((s*64 + l4*16) ^ psw));
            bf16x8 pb1 = *(const bf16x8*)(Pw + (16 + l15)*128 + ((s*64 + l4*16) ^ psw));
            #pragma unroll
            for (int m = 0; m < 4; ++m) {
                bf16x8 vb = *(const bf16x8*)(Vs[cur] + (m*16 + l15)*128 + ((l4*16 + s*64) ^ rsw));
                o[0][m] = __builtin_amdgcn_mfma_f32_16x16x32_bf16(vb, pb0, o[0][m], 0, 0, 0);
                o[1][m] = __builtin_amdgcn_mfma_f32_16x16x32_bf16(vb, pb1, o[1][m], 0, 0, 0);
            }
        }
        __builtin_amdgcn_s_setprio(0);

        __builtin_amdgcn_s_barrier();   // reads of buf[cur] consumed -> overwrite safe
    }

    // l reduce across the 4 lanes sharing each q (xor 16, 32)
    #pragma unroll
    for (int qg = 0; qg < 2; ++qg) {
        l_run[qg] += __shfl_xor(l_run[qg], 16, 64);
        l_run[qg] += __shfl_xor(l_run[qg], 32, 64);
    }
    const float inv0 = 1.f / l_run[0], inv1 = 1.f / l_run[1];

    // epilogue: stage O rows [32 q][132B], then 128B-contiguous stores
    const int b = bh / HEADS, h = bh % HEADS;
    #pragma unroll
    for (int m = 0; m < 4; ++m)
        #pragma unroll
        for (int r = 0; r < 4; ++r) {
            *(u16*)(Pw + l15*132        + (m*16 + l4*4 + r)*2) = f2b_rne(o[0][m][r] * inv0);
            *(u16*)(Pw + (16 + l15)*132 + (m*16 + l4*4 + r)*2) = f2b_rne(o[1][m][r] * inv1);
        }
    #pragma unroll
    for (int i = 0; i < 4; ++i) {
        int row = i*8 + (lane >> 3);              // q-row within wave's 32
        int d0  = (lane & 7) * 8;
        uint4 val = *(const uint4*)(Pw + row*132 + d0*2);
        int tok = qt*128 + w*32 + row;
        *(uint4*)(A + (((size_t)b * N_ + tok) * HEADS + h) * HDIM + d0) = val;
    }
}

// -------------------- Kernel 3: output projection (dbuf + counted vmcnt, fp32 out) --------------------
__global__ __launch_bounds__(256) void proj_gemm(
    const u16* __restrict__ Ab, const u16* __restrict__ wb,
    const float* __restrict__ bias, float* __restrict__ out)
{
    __shared__ __align__(16) unsigned char Asl[2][128*128];
    __shared__ __align__(16) unsigned char Bsl[2][128*128];
    const int t = threadIdx.x;
    const int lane = t & 63, wid = t >> 6;
    const int wr = wid >> 1, wc = wid & 1;
    const int l15 = lane & 15, l4 = lane >> 4;
    const int lr  = lane >> 3;
    const int lcs = ((lane & 7) ^ lr & 7) * 16;
    const int rsw = (l15 & 7) << 4;

    const int b0 = blockIdx.x;
    const int lg = (b0 & 7) * 48 + (b0 >> 3);
    const int col0 = (lg % 6) * 128, row0 = (lg / 6) * 128;

    f32x4 acc[4][4];
    #pragma unroll
    for (int m = 0; m < 4; ++m)
        #pragma unroll
        for (int n = 0; n < 4; ++n) acc[m][n] = f32x4{0.f,0.f,0.f,0.f};

    const unsigned char* aSrc = (const unsigned char*)Ab + (size_t)(row0 + lr)*1536 + lcs;
    const unsigned char* bSrc = (const unsigned char*)wb + (size_t)(col0 + lr)*1536 + lcs;

    auto stage = [&](int buf, int k0s){
        #pragma unroll
        for (int c = 0; c < 4; ++c) {
            int rg = wid*32 + c*8;
            gl_lds16(aSrc + (size_t)rg*1536 + k0s*2, Asl[buf] + rg*128);
            gl_lds16(bSrc + (size_t)rg*1536 + k0s*2, Bsl[buf] + rg*128);
        }
    };

    stage(0, 0);

    for (int step = 0; step < 12; ++step) {
        const int cur = step & 1;
        if (step < 11) {
            stage(cur ^ 1, (step + 1) * 64);
            asm volatile("s_waitcnt vmcnt(8)" ::: "memory");
        } else {
            asm volatile("s_waitcnt vmcnt(0)" ::: "memory");
        }
        __builtin_amdgcn_s_barrier();

        #pragma unroll
        for (int s = 0; s < 2; ++s) {
            bf16x8 af[4], bfr[4];
            #pragma unroll
            for (int m = 0; m < 4; ++m)
                af[m] = *(const bf16x8*)(Asl[cur] + (wr*64 + m*16 + l15)*128 + ((l4*16 + s*64) ^ rsw));
            #pragma unroll
            for (int n = 0; n < 4; ++n)
                bfr[n] = *(const bf16x8*)(Bsl[cur] + (wc*64 + n*16 + l15)*128 + ((l4*16 + s*64) ^ rsw));
            #pragma unroll
            for (int m = 0; m < 4; ++m)
                #pragma unroll
                for (int n = 0; n < 4; ++n)
                    acc[m][n] = __builtin_amdgcn_mfma_f32_16x16x32_bf16(af[m], bfr[n], acc[m][n], 0, 0, 0);
        }
        __builtin_amdgcn_s_barrier();
    }

    float bias_v[4];
    #pragma unroll
    for (int n = 0; n < 4; ++n) bias_v[n] = bias[col0 + wc*64 + n*16 + l15];
    #pragma unroll
    for (int m = 0; m < 4; ++m)
        #pragma unroll
        for (int r = 0; r < 4; ++r) {
            int rg = row0 + wr*64 + m*16 + l4*4 + r;
            #pragma unroll
            for (int n = 0; n < 4; ++n)
                out[(size_t)rg * DIM + col0 + wc*64 + n*16 + l15] = acc[m][n][r] + bias_v[n];
        }
}

extern "C" void kernel_launch(void* const* d_in, const int* in_sizes, int n_in,
                              void* d_out, int out_size, void* d_ws, size_t ws_size,
                              hipStream_t stream)
{
    const float* x      = (const float*)d_in[0];
    const float* qkv_w  = (const float*)d_in[1];
    const float* qkv_b  = (const float*)d_in[2];
    const float* qn_w   = (const float*)d_in[3];
    const float* qn_b   = (const float*)d_in[4];
    const float* kn_w   = (const float*)d_in[5];
    const float* kn_b   = (const float*)d_in[6];
    const float* proj_w = (const float*)d_in[7];
    const float* proj_b = (const float*)d_in[8];
    float* out = (float*)d_out;

    const size_t XE  = (size_t)B_ * N_ * DIM;   // 6291456
    const size_t QWE = (size_t)3 * DIM * DIM;   // 1769472
    const size_t PWE = (size_t)DIM * DIM;       // 589824

    u16* xb  = (u16*)d_ws;
    u16* qwb = xb  + XE;
    u16* pwb = qwb + QWE;
    u16* Qb  = pwb + PWE;
    u16* Kb  = Qb  + XE;
    u16* VTb = Kb  + XE;
    u16* Ab  = VTb + XE;    // total 67.6 MB

    const int n0 = (int)(XE/8), n1 = (int)(QWE/8), n2 = (int)(PWE/8);
    cast3_kernel<<<(n0 + n1 + n2 + 255)/256, 256, 0, stream>>>(x, xb, n0, qkv_w, qwb, n1, proj_w, pwb, n2);

    qkv_gemm_ln<<<dim3(1152), 256, 0, stream>>>(xb, qwb, qkv_b, qn_w, qn_b,
                                                kn_w, kn_b, Qb, Kb, VTb);
    attn_mfma<<<dim3(768), 256, 0, stream>>>(Qb, Kb, VTb, Ab);
    proj_gemm<<<dim3(384), 256, 0, stream>>>(Ab, pwb, proj_b, out);
}